// Round 14
// baseline (111.563 us; speedup 1.0000x reference)
//
#include <hip/hip_runtime.h>

// CCAMDec: out = x + scale * softmax(max_k(E)-E) @ y,  E = x·yᵀ over HW
// N=8, C=512, K=64, HW=4096. softmax(max-E) == softmax(-E) (shift invariance).
#define N_ 8
#define C_ 512
#define K_ 64
#define HW_ 4096
#define NSP 4                   // s-splits per (n,ct)
#define SRANGE (HW_ / NSP)      // 1024 s per k_esm block
#define SCHUNK 128              // s per staged chunk
#define NCH 8                   // chunks per block

typedef __attribute__((ext_vector_type(8))) short short8;   // 8 bf16 (4 VGPRs) MFMA A/B frag
typedef __attribute__((ext_vector_type(4))) float floatx4;  // MFMA C/D frag

// 8 f32 -> 8 bf16 via hardware v_cvt_pk_bf16_f32 (RNE, 1 instr / 2 elems)
__device__ __forceinline__ short8 cvt8(const float* __restrict__ p){
  float4 u = *(const float4*)p;
  float4 w = *(const float4*)(p + 4);
  union { unsigned u32[4]; short8 s; } r;
  asm("v_cvt_pk_bf16_f32 %0, %1, %2" : "=v"(r.u32[0]) : "v"(u.x), "v"(u.y));
  asm("v_cvt_pk_bf16_f32 %0, %1, %2" : "=v"(r.u32[1]) : "v"(u.z), "v"(u.w));
  asm("v_cvt_pk_bf16_f32 %0, %1, %2" : "=v"(r.u32[2]) : "v"(w.x), "v"(w.y));
  asm("v_cvt_pk_bf16_f32 %0, %1, %2" : "=v"(r.u32[3]) : "v"(w.z), "v"(w.w));
  return r.s;
}

// async global -> LDS, 16 B/lane (1 KB/wave), zero VGPR cost
__device__ __forceinline__ void gload16(const void* g, void* l){
  __builtin_amdgcn_global_load_lds(
      (const __attribute__((address_space(1))) void*)g,
      (__attribute__((address_space(3))) void*)l, 16, 0, 0);
}

// K0: y (f32, [n][k][s]) -> ybf (bf16 row-major [n][k][s]) and ytr (bf16 [n][s][k])
__global__ __launch_bounds__(256) void k_prep(const float* __restrict__ y,
                                              unsigned short* __restrict__ ybf,
                                              unsigned short* __restrict__ ytr){
  __shared__ unsigned short tile[64][72];
  int n  = blockIdx.x >> 6;                 // 64 s-tiles per batch
  int s0 = (blockIdx.x & 63) << 6;
  int tid = threadIdx.x;
  int k  = tid >> 2;
  int sc = (tid & 3) << 4;
  const float* yp = y + ((size_t)n * K_ + k) * HW_ + s0 + sc;
  union { unsigned short u16[16]; short8 s8[2]; uint4 q[2]; } u;
  u.s8[0] = cvt8(yp);
  u.s8[1] = cvt8(yp + 8);
  unsigned short* rp = ybf + ((size_t)n * K_ + k) * HW_ + s0 + sc;
  *(uint4*)rp       = u.q[0];
  *(uint4*)(rp + 8) = u.q[1];
#pragma unroll
  for (int j = 0; j < 16; ++j) tile[sc + j][k] = u.u16[j];
  __syncthreads();
  int s  = tid >> 2;
  int kc = (tid & 3) << 4;
  unsigned short* tp = ytr + ((size_t)n * HW_ + s0 + s) * K_ + kc;
  *(uint4*)tp       = *(const uint4*)&tile[s][kc];
  *(uint4*)(tp + 8) = *(const uint4*)&tile[s][kc + 8];
}

// K1: energy + last-block softmax.  Block = (n, 16c, 1024s), 4 waves,
// 8 chunks of 128s, 2-buffer gload_lds + counted vmcnt(6) (R10 core).
// Wave w owns s-slice w of each chunk, all 4 k-quadrants (acc[4]).
// Epilogue: intra-block LDS reduce (aliased onto drained staging) ->
// 1024 atomicAdd f32 into eacc[(n,ct)] (4 KB) -> ticket; the LAST of the
// 4 sp-blocks re-reads eacc (agent-scope atomic loads), does softmax(-E),
// writes att.  Nobody spins -> no co-residency assumption (R12 lesson).
__global__ __launch_bounds__(256) void k_esm(const float* __restrict__ x,
                                             const unsigned short* __restrict__ ybf,
                                             float* __restrict__ eacc,
                                             unsigned* __restrict__ cnt,
                                             unsigned short* __restrict__ att){
  __shared__ char smem[49152];
  __shared__ unsigned tk;
  const int bid = ((blockIdx.x & 7) << 7) | (blockIdx.x >> 3);  // XCD swizzle (1024%8==0)
  const int sp = bid & 3;
  const int ct = (bid >> 2) & 31;
  const int n  = bid >> 7;
  const int tid = threadIdx.x;
  const int w = tid >> 6, l = tid & 63;
  const int lo = l & 15, hi = l >> 4;
  const int c0 = ct << 4;
  const int sb = sp * SRANGE;
  const int pg = (n << 5) + ct;

  // chunk-invariant per-lane source addresses (bytes), pre-swizzled
  const int ar0 = ((w << 1) + 0) * 2 + (l >> 5);
  const int ar1 = ((w << 1) + 1) * 2 + (l >> 5);
  const char* asrc0 = (const char*)(x + ((size_t)n * C_ + c0 + ar0) * HW_ + sb)
                      + ((16 * (l & 31)) ^ ((ar0 & 7) << 4));
  const char* asrc1 = (const char*)(x + ((size_t)n * C_ + c0 + ar1) * HW_ + sb)
                      + ((16 * (l & 31)) ^ ((ar1 & 7) << 4));
  const char* bsrc[4];
#pragma unroll
  for (int j = 0; j < 4; ++j){
    int kk = ((w << 2) + j) * 4 + (l >> 4);
    bsrc[j] = (const char*)(ybf + ((size_t)n * K_ + kk) * HW_ + sb)
              + ((16 * (l & 15)) ^ ((kk & 7) << 4));
  }

  floatx4 acc[4];
#pragma unroll
  for (int q = 0; q < 4; ++q) acc[q] = (floatx4){0.f, 0.f, 0.f, 0.f};
  const int aswz = (lo & 7) << 4;

#define AS(BUF) (smem + (BUF) * 24576)
#define BS(BUF) (smem + (BUF) * 24576 + 8192)
#define STAGE(BUF, CH)                                                         \
  {                                                                            \
    gload16(asrc0 + (size_t)(CH) * (SCHUNK * 4), AS(BUF) + (((w << 1) + 0) << 10)); \
    gload16(asrc1 + (size_t)(CH) * (SCHUNK * 4), AS(BUF) + (((w << 1) + 1) << 10)); \
    _Pragma("unroll")                                                          \
    for (int j = 0; j < 4; ++j)                                                \
      gload16(bsrc[j] + (size_t)(CH) * (SCHUNK * 2), BS(BUF) + (((w << 2) + j) << 10)); \
  }

  STAGE(0, 0)

#pragma unroll
  for (int ch = 0; ch < NCH; ++ch){
    const int cur = ch & 1;
    if (ch + 1 < NCH){
      STAGE(cur ^ 1, ch + 1)
      asm volatile("s_waitcnt vmcnt(6)" ::: "memory");   // chunk ch complete
    } else {
      asm volatile("s_waitcnt vmcnt(0)" ::: "memory");
    }
    __builtin_amdgcn_s_barrier();
    __builtin_amdgcn_sched_barrier(0);
    {
      // wave's own s-slice (32 s of the 128-s chunk)
      int ao = (w << 7) + (hi << 5);
      const char* ab = AS(cur) + (lo << 9);
      float4 a0f = *(const float4*)(ab + ((ao     ) ^ aswz));
      float4 a1f = *(const float4*)(ab + ((ao + 16) ^ aswz));
      union { unsigned u32[4]; short8 s; } af;
      asm("v_cvt_pk_bf16_f32 %0, %1, %2" : "=v"(af.u32[0]) : "v"(a0f.x), "v"(a0f.y));
      asm("v_cvt_pk_bf16_f32 %0, %1, %2" : "=v"(af.u32[1]) : "v"(a0f.z), "v"(a0f.w));
      asm("v_cvt_pk_bf16_f32 %0, %1, %2" : "=v"(af.u32[2]) : "v"(a1f.x), "v"(a1f.y));
      asm("v_cvt_pk_bf16_f32 %0, %1, %2" : "=v"(af.u32[3]) : "v"(a1f.z), "v"(a1f.w));
#pragma unroll
      for (int q = 0; q < 4; ++q){
        short8 b = *(const short8*)(BS(cur) + ((q << 4) + lo) * 256
                                    + (((w << 6) + (hi << 4)) ^ aswz));
        // swapped: A = y-frag (M=k), B = x-frag (N=c) -> D col=lo->c, row->k
        acc[q] = __builtin_amdgcn_mfma_f32_16x16x32_bf16(b, af.s, acc[q], 0, 0, 0);
      }
    }
    __builtin_amdgcn_sched_barrier(0);
    __builtin_amdgcn_s_barrier();
  }
#undef STAGE

  // ---- intra-block reduce (alias Els onto drained staging) ----
  float (*Els)[16][64] = (float (*)[16][64])smem;   // 16 KB
#pragma unroll
  for (int q = 0; q < 4; ++q)
    *(floatx4*)&Els[w][lo][(q << 4) + (hi << 2)] = acc[q];
  __syncthreads();

  if (tid < 256){
    int c = tid >> 4, j = tid & 15;
    float4 e = *(const float4*)&Els[0][c][4 * j];
    float4 t1 = *(const float4*)&Els[1][c][4 * j];
    float4 t2 = *(const float4*)&Els[2][c][4 * j];
    float4 t3 = *(const float4*)&Els[3][c][4 * j];
    e.x += t1.x + t2.x + t3.x; e.y += t1.y + t2.y + t3.y;
    e.z += t1.z + t2.z + t3.z; e.w += t1.w + t2.w + t3.w;
    float* dst = eacc + ((size_t)pg << 10) + (c << 6) + (j << 2);
    atomicAdd(dst + 0, e.x);
    atomicAdd(dst + 1, e.y);
    atomicAdd(dst + 2, e.z);
    atomicAdd(dst + 3, e.w);
  }
  __syncthreads();                    // all atomics issued+complete (vmcnt drain)
  if (tid == 0){
    __threadfence();                  // release
    tk = atomicAdd(&cnt[pg], 1u);
  }
  __syncthreads();
  if (tk != NSP - 1) return;          // not last -> done, no waiting

  // ---- last block: finalize softmax(-E) ----
  __threadfence();                    // acquire
  if (tid < 256){
    int c = tid >> 4, j = tid & 15;
    const float* src = eacc + ((size_t)pg << 10) + (c << 6) + (j << 2);
    float e0 = __hip_atomic_load(src + 0, __ATOMIC_RELAXED, __HIP_MEMORY_SCOPE_AGENT);
    float e1 = __hip_atomic_load(src + 1, __ATOMIC_RELAXED, __HIP_MEMORY_SCOPE_AGENT);
    float e2 = __hip_atomic_load(src + 2, __ATOMIC_RELAXED, __HIP_MEMORY_SCOPE_AGENT);
    float e3 = __hip_atomic_load(src + 3, __ATOMIC_RELAXED, __HIP_MEMORY_SCOPE_AGENT);
    float m = fminf(fminf(e0, e1), fminf(e2, e3));
#pragma unroll
    for (int off = 8; off; off >>= 1) m = fminf(m, __shfl_xor(m, off, 16));
    float p0 = __expf(m - e0), p1 = __expf(m - e1);
    float p2 = __expf(m - e2), p3 = __expf(m - e3);
    float s = p0 + p1 + p2 + p3;
#pragma unroll
    for (int off = 8; off; off >>= 1) s += __shfl_xor(s, off, 16);
    float inv = 1.f / s;
    unsigned d0, d1;
    asm("v_cvt_pk_bf16_f32 %0, %1, %2" : "=v"(d0) : "v"(p0 * inv), "v"(p1 * inv));
    asm("v_cvt_pk_bf16_f32 %0, %1, %2" : "=v"(d1) : "v"(p2 * inv), "v"(p3 * inv));
    uint2 dd; dd.x = d0; dd.y = d1;
    *(uint2*)(att + ((size_t)n * C_ + c0 + c) * K_ + 4 * j) = dd;
  }
#undef AS
#undef BS
}

// K2: out = x + scale * att @ y.  Grid 2048 (4-8 blocks/CU), 256 thr.
// att (L2-hot) -> XOR-swizzled LDS -> B frags.  Swapped MFMA, A straight
// from ytr; T[16][68] transpose -> 256B-contiguous x-load / out-store.
__global__ __launch_bounds__(256) void k_pv(const float* __restrict__ x,
                                            const unsigned short* __restrict__ att,
                                            const unsigned short* __restrict__ ytr,
                                            const float* __restrict__ scale,
                                            float* __restrict__ out){
  __shared__ float T[4][16][68];
  __shared__ char attl[2048];
  int bid = ((blockIdx.x & 7) << 8) | (blockIdx.x >> 3);  // XCD swizzle (2048%8==0)
  int sb = bid & 7;
  int ct = (bid >> 3) & 31;
  int n  = bid >> 8;
  int tid = threadIdx.x;
  int w  = tid >> 6;
  int l  = tid & 63, lo = l & 15, hi = l >> 4;
  int c0 = ct << 4;
  int sP = (sb << 9) + (w << 7);     // 512 per block, 128 per wave
  float sc = scale[0];

  if (tid < 256){
    int c = tid >> 4, j = tid & 15;
    uint2 dd = *(const uint2*)(att + ((size_t)n * C_ + c0 + c) * K_ + 4 * j);
    *(uint2*)(attl + c * 128 + ((8 * j) ^ ((c & 7) << 4))) = dd;
  }
  __syncthreads();

  short8 batt0 = *(const short8*)(attl + lo * 128 + ((     hi * 16) ^ ((lo & 7) << 4)));
  short8 batt1 = *(const short8*)(attl + lo * 128 + ((64 + hi * 16) ^ ((lo & 7) << 4)));
  const unsigned short* ybn = ytr + (size_t)n * HW_ * K_;
  float (*Tw)[68] = T[w];
  size_t xb[4];
#pragma unroll
  for (int rg = 0; rg < 4; ++rg)
    xb[rg] = ((size_t)n * C_ + c0 + (rg << 2) + hi) * HW_ + sP + (lo << 2);

  short8 aA[8]; float4 xA[4];
  short8 aB[8]; float4 xB[4];

#define PVLOAD(G, AV, XV)                                                      \
  {                                                                            \
    int sg = sP + (G) * 64;                                                    \
    _Pragma("unroll")                                                          \
    for (int t = 0; t < 4; ++t){                                               \
      const unsigned short* ap = ybn + (size_t)(sg + t * 16 + lo) * K_ + (hi << 3); \
      AV[2 * t]     = *(const short8*)(ap);                                    \
      AV[2 * t + 1] = *(const short8*)(ap + 32);                               \
    }                                                                          \
    _Pragma("unroll")                                                          \
    for (int rg = 0; rg < 4; ++rg)                                             \
      XV[rg] = *(const float4*)(x + xb[rg] + (G) * 64);                        \
  }

#define PVCOMP(G, AV, XV)                                                      \
  {                                                                            \
    _Pragma("unroll")                                                          \
    for (int t = 0; t < 4; ++t){                                               \
      floatx4 a2 = {0.f, 0.f, 0.f, 0.f};                                       \
      a2 = __builtin_amdgcn_mfma_f32_16x16x32_bf16(AV[2 * t],     batt0, a2, 0, 0, 0); \
      a2 = __builtin_amdgcn_mfma_f32_16x16x32_bf16(AV[2 * t + 1], batt1, a2, 0, 0, 0); \
      *(floatx4*)&Tw[lo][t * 16 + (hi << 2)] = a2;   /* D: col=lo->c, row->s */ \
    }                                                                          \
    _Pragma("unroll")                                                          \
    for (int rg = 0; rg < 4; ++rg){                                            \
      float4 v  = *(const float4*)&Tw[(rg << 2) + hi][lo << 2];                \
      float4 xv = XV[rg];                                                      \
      float4 o;                                                                \
      o.x = xv.x + sc * v.x; o.y = xv.y + sc * v.y;                            \
      o.z = xv.z + sc * v.z; o.w = xv.w + sc * v.w;                            \
      *(float4*)(out + xb[rg] + (G) * 64) = o;                                 \
    }                                                                          \
  }

  PVLOAD(0, aA, xA)
  PVLOAD(1, aB, xB)
  PVCOMP(0, aA, xA)
  PVCOMP(1, aB, xB)
#undef PVLOAD
#undef PVCOMP
}

extern "C" void kernel_launch(void* const* d_in, const int* in_sizes, int n_in,
                              void* d_out, int out_size, void* d_ws, size_t ws_size,
                              hipStream_t stream){
  const float* x     = (const float*)d_in[0];
  const float* y     = (const float*)d_in[1];
  const float* scale = (const float*)d_in[2];
  float* out = (float*)d_out;

  // ws layout (10.5 MiB):
  //   eacc : 256 * 1024 f32 = 1 MiB  @ 0        (zeroed every launch)
  //   cnt  : 256 u32        = 1 KiB  @ 1 MiB    (zeroed every launch)
  //   att  : N*C*K bf16     = 512 KiB @ 1 MiB + 4 KiB
  //   ybf  : N*K*HW bf16    = 4 MiB  @ 2 MiB
  //   ytr  : N*HW*K bf16    = 4 MiB  @ 6 MiB
  char* ws = (char*)d_ws;
  float*          eacc = (float*)(ws);
  unsigned*       cnt  = (unsigned*)(ws + (1u<<20));
  unsigned short* att  = (unsigned short*)(ws + (1u<<20) + 4096);
  unsigned short* ybf  = (unsigned short*)(ws + (2u<<20));
  unsigned short* ytr  = (unsigned short*)(ws + (6u<<20));

  hipMemsetAsync(eacc, 0, (1u<<20) + 1024, stream);   // eacc + cnt
  k_prep <<<N_ * (HW_/64), 256, 0, stream>>>(y, ybf, ytr);
  k_esm  <<<N_ * 32 * NSP, 256, 0, stream>>>(x, ybf, eacc, cnt, att);
  k_pv   <<<N_ * 32 * 8,   256, 0, stream>>>(x, att, ytr, scale, out);
}